// Round 2
// baseline (213.021 us; speedup 1.0000x reference)
//
#include <hip/hip_runtime.h>

#define B_TOT 65536
#define R 12
#define L 16
#define NB 16
#define NEG_MIN -3.402823466e38f

// ws layout (float index):
//   [0,32)   v[j]  (kw2 . qb2)
//   [32]     c     (qb2 . kb2)
//   [40,52)  pmask (as int: bit l set if freq_mask[r][l] != 0)
//   [64,96)  sorted breakpoints t[32]
//   [96, 96+33*72) interval table: row m (72 floats, 288 B):
//        [0,32) A_m   [32] Au_m   [33,36) pad
//        [36,68) B_m  [68] Bu_m   [69,72) pad
#define WS_V   0
#define WS_C   32
#define WS_PM  40
#define WS_BP  64
#define WS_TAB 96
#define TROW   72

__global__ __launch_bounds__(256) void nfh_pre(
    const float* __restrict__ qw1, const float* __restrict__ qb1,
    const float* __restrict__ qw2, const float* __restrict__ qb2,
    const float* __restrict__ kw2, const float* __restrict__ kb2,
    const int*   __restrict__ fmask,
    float* __restrict__ ws)
{
    __shared__ float sM[1024];     // M[i][j] = sum_h qw2[i,h]*kw2[j,h]
    __shared__ float su[32];       // u[i] = qw2[i,:] . kb2
    __shared__ float sw1[32], sb1[32], sbp[32];
    const int t = threadIdx.x;

    if (t < 32) { sw1[t] = qw1[t]; sb1[t] = qb1[t]; }
    for (int e = t; e < 1024; e += 256) {
        const int i = e >> 5, j = e & 31;
        float acc = 0.f;
        for (int h = 0; h < 64; ++h) acc = fmaf(qw2[i * 64 + h], kw2[j * 64 + h], acc);
        sM[e] = acc;
    }
    if (t < 32) {
        float au = 0.f, av = 0.f;
        for (int h = 0; h < 64; ++h) {
            au = fmaf(qw2[t * 64 + h], kb2[h], au);
            av = fmaf(kw2[t * 64 + h], qb2[h], av);
        }
        su[t] = au;
        ws[WS_V + t] = av;
        const float w = qw1[t];
        sbp[t] = (w != 0.f) ? (-qb1[t] / w) : 3.0e30f;
    }
    if (t == 64) {
        float acc = 0.f;
        for (int h = 0; h < 64; ++h) acc = fmaf(qb2[h], kb2[h], acc);
        ws[WS_C] = acc;
    }
    if (t < 12) {
        int pm = 0;
        for (int l = 0; l < 16; ++l) if (fmask[t * 16 + l] != 0) pm |= (1 << l);
        ((int*)ws)[WS_PM + t] = pm;
    }
    __syncthreads();
    if (t == 0) { // insertion sort breakpoints
        for (int i = 1; i < 32; ++i) {
            float key = sbp[i]; int j = i - 1;
            while (j >= 0 && sbp[j] > key) { sbp[j + 1] = sbp[j]; --j; }
            sbp[j + 1] = key;
        }
    }
    __syncthreads();
    if (t < 32) ws[WS_BP + t] = sbp[t];

    // Build interval table: 33 intervals x (32 cols + Au/Bu)
    for (int task = t; task < 33 * 32 + 33; task += 256) {
        const int m = (task < 33 * 32) ? (task >> 5) : (task - 33 * 32);
        const float xi = (m == 0) ? sbp[0] - 1.f
                       : ((m == 32) ? sbp[31] + 1.f
                                    : sbp[m - 1] + 0.5f * (sbp[m] - sbp[m - 1]));
        if (task < 33 * 32) {
            const int j = task & 31;
            float A = 0.f, Bv = 0.f;
            for (int i = 0; i < 32; ++i) {
                if (fmaf(sw1[i], xi, sb1[i]) > 0.f) {
                    A  = fmaf(sw1[i], sM[i * 32 + j], A);
                    Bv = fmaf(sb1[i], sM[i * 32 + j], Bv);
                }
            }
            ws[WS_TAB + m * TROW + j] = A;
            ws[WS_TAB + m * TROW + 36 + j] = Bv;
        } else {
            float Au = 0.f, Bu = 0.f;
            for (int i = 0; i < 32; ++i) {
                if (fmaf(sw1[i], xi, sb1[i]) > 0.f) {
                    Au = fmaf(sw1[i], su[i], Au);
                    Bu = fmaf(sb1[i], su[i], Bu);
                }
            }
            ws[WS_TAB + m * TROW + 32] = Au;
            ws[WS_TAB + m * TROW + 36 + 32] = Bu;
        }
    }
}

__global__ __launch_bounds__(256, 4) void nfh_main(
    const float* __restrict__ rss,   // [B,R]
    const float* __restrict__ feat,  // [B,L,F]
    const float* __restrict__ pos,   // [B,L,3]
    const float* __restrict__ prev,  // [B,3]
    const float* __restrict__ gw1, const float* __restrict__ gb1,
    const float* __restrict__ gw2, const float* __restrict__ gb2,
    const float* __restrict__ kw1, const float* __restrict__ kb1,
    const float* __restrict__ sigma_p,
    const float* __restrict__ ws,
    float* __restrict__ out)
{
    __shared__ float s_dA[NB * 196];  // [bb][u*16 + l], u<12
    __shared__ float s_dB[NB * 196];
    __shared__ int   s_km[NB * 34];   // mark, then slot index per k
    __shared__ int   s_kl[NB * 12];   // distinct-k list
    __shared__ int   s_nk[NB];

    const int t = threadIdx.x;
    const int b0 = blockIdx.x * NB;
    const float sigma = sigma_p[0];
    const float inv2s2 = 1.f / (2.f * sigma * sigma);
    const float* __restrict__ tab = ws + WS_TAB;

    for (int e = t; e < NB * 34; e += 256) s_km[e] = -1;
    __syncthreads();

    // ---------- P1: t = (bb1, l1): key hidden bh[32] + vbl (registers) ----------
    const int bb1 = t >> 4, l1 = t & 15;
    float bh[32];
    float vbl;
    {
        const int b = b0 + bb1;
        float in[11];
        const float4* f4 = (const float4*)(feat + ((size_t)b * (L * 8) + l1 * 8));
        const float4 fa = f4[0], fb = f4[1];
        in[0] = fa.x; in[1] = fa.y; in[2] = fa.z; in[3] = fa.w;
        in[4] = fb.x; in[5] = fb.y; in[6] = fb.z; in[7] = fb.w;
        const float* pp = pos + ((size_t)b * (L * 3) + l1 * 3);
        in[8] = pp[0]; in[9] = pp[1]; in[10] = pp[2];

        float dsq = 0.f;
        #pragma unroll
        for (int m = 0; m < 3; ++m) {
            const float d = prev[b * 3 + m] - in[8 + m];
            dsq = fmaf(d, d, dsq);
        }
        #pragma unroll
        for (int j = 0; j < 32; ++j) bh[j] = kb1[j];
        #pragma unroll
        for (int m = 0; m < 11; ++m) {
            const float im = in[m];
            #pragma unroll
            for (int j = 0; j < 32; ++j) bh[j] = fmaf(im, kw1[m * 32 + j], bh[j]);
        }
        float vb = ws[WS_C];
        #pragma unroll
        for (int j = 0; j < 32; ++j) {
            bh[j] = fmaxf(bh[j], 0.f);
            vb = fmaf(ws[WS_V + j], bh[j], vb);
        }
        vbl = vb - dsq * inv2s2;
    }

    // ---------- P2a: t < 192: (bb2, r2) — gate, xq, interval k, mark ----------
    float xq = 0.f, iw = 0.f;
    int kk = 0, bb2 = 0;
    if (t < NB * R) {
        bb2 = t / R;
        const float x = rss[(size_t)b0 * R + t];
        float z = gb2[0];
        #pragma unroll
        for (int i = 0; i < 16; ++i) {
            const float h = fmaxf(fmaf(x, gw1[i], gb1[i]), 0.f);
            z = fmaf(h, gw2[i], z);
        }
        const float gate = 1.f / (1.f + __expf(-z));
        iw = (x > 0.5f) ? gate : 0.f;
        out[(size_t)B_TOT * R * L + (size_t)b0 * R + t] = iw;
        xq = x * iw;
        #pragma unroll
        for (int m = 0; m < 32; ++m) kk += (xq > ws[WS_BP + m]) ? 1 : 0;
        s_km[bb2 * 34 + kk] = 1;
    }
    __syncthreads();

    // ---------- dedup scan: t < 16 builds distinct-k list + slot map ----------
    if (t < NB) {
        int n = 0;
        for (int k = 0; k < 33; ++k) {
            if (s_km[t * 34 + k] >= 0) { s_kl[t * 12 + n] = k; s_km[t * 34 + k] = n; ++n; }
        }
        s_nk[t] = n;
    }
    __syncthreads();

    // ---------- P2b: t = (bb1, l1): per distinct k, dotA(l), dotB(l) ----------
    {
        const int n = s_nk[bb1];
        for (int u = 0; u < n; ++u) {
            const int k = s_kl[bb1 * 12 + u];
            const float* row = tab + k * TROW;
            const float4* ra = (const float4*)row;
            const float4* rb = (const float4*)(row + 36);
            float dA = row[32];       // Au
            float dB = row[68] + vbl; // Bu + vb_l
            #pragma unroll
            for (int q = 0; q < 8; ++q) {
                const float4 a4 = ra[q];
                dA = fmaf(a4.x, bh[q * 4 + 0], dA);
                dA = fmaf(a4.y, bh[q * 4 + 1], dA);
                dA = fmaf(a4.z, bh[q * 4 + 2], dA);
                dA = fmaf(a4.w, bh[q * 4 + 3], dA);
            }
            #pragma unroll
            for (int q = 0; q < 8; ++q) {
                const float4 b4 = rb[q];
                dB = fmaf(b4.x, bh[q * 4 + 0], dB);
                dB = fmaf(b4.y, bh[q * 4 + 1], dB);
                dB = fmaf(b4.z, bh[q * 4 + 2], dB);
                dB = fmaf(b4.w, bh[q * 4 + 3], dB);
            }
            s_dA[bb1 * 196 + u * 16 + l1] = dA;
            s_dB[bb1 * 196 + u * 16 + l1] = dB;
        }
    }
    __syncthreads();

    // ---------- P3: t < 192: (bb2, r2) — scores, mask, softmax, store ----------
    if (t < NB * R) {
        const int r2 = t - bb2 * R;
        const int u = s_km[bb2 * 34 + kk];
        const float4* pa = (const float4*)&s_dA[bb2 * 196 + u * 16];
        const float4* pb = (const float4*)&s_dB[bb2 * 196 + u * 16];
        const int pm = ((const int*)ws)[WS_PM + r2];

        float sc[16];
        #pragma unroll
        for (int q = 0; q < 4; ++q) {
            const float4 a4 = pa[q], b4 = pb[q];
            sc[q * 4 + 0] = fmaf(xq, a4.x, b4.x);
            sc[q * 4 + 1] = fmaf(xq, a4.y, b4.y);
            sc[q * 4 + 2] = fmaf(xq, a4.z, b4.z);
            sc[q * 4 + 3] = fmaf(xq, a4.w, b4.w);
        }
        #pragma unroll
        for (int l = 0; l < 16; ++l)
            if (!((pm >> l) & 1)) sc[l] = NEG_MIN;

        float mx = sc[0];
        #pragma unroll
        for (int l = 1; l < 16; ++l) mx = fmaxf(mx, sc[l]);
        float sum = 0.f;
        #pragma unroll
        for (int l = 0; l < 16; ++l) { sc[l] = __expf(sc[l] - mx); sum += sc[l]; }
        const float inv = 1.f / sum;

        float4* op4 = (float4*)(out + (size_t)((size_t)(b0 + bb2) * R + r2) * L);
        #pragma unroll
        for (int q = 0; q < 4; ++q)
            op4[q] = make_float4(sc[q * 4] * inv, sc[q * 4 + 1] * inv,
                                 sc[q * 4 + 2] * inv, sc[q * 4 + 3] * inv);
    }
}

extern "C" void kernel_launch(void* const* d_in, const int* in_sizes, int n_in,
                              void* d_out, int out_size, void* d_ws, size_t ws_size,
                              hipStream_t stream) {
    const float* rss   = (const float*)d_in[0];
    const float* feat  = (const float*)d_in[1];
    const float* pos   = (const float*)d_in[2];
    const float* prev  = (const float*)d_in[3];
    const int*   fmask = (const int*)d_in[4];
    const float* gw1   = (const float*)d_in[5];
    const float* gb1   = (const float*)d_in[6];
    const float* gw2   = (const float*)d_in[7];
    const float* gb2   = (const float*)d_in[8];
    const float* qw1   = (const float*)d_in[9];
    const float* qb1   = (const float*)d_in[10];
    const float* qw2   = (const float*)d_in[11];
    const float* qb2   = (const float*)d_in[12];
    const float* kw1   = (const float*)d_in[13];
    const float* kb1   = (const float*)d_in[14];
    const float* kw2   = (const float*)d_in[15];
    const float* kb2   = (const float*)d_in[16];
    const float* sigma = (const float*)d_in[17];
    float* out = (float*)d_out;
    float* ws  = (float*)d_ws;

    nfh_pre<<<1, 256, 0, stream>>>(qw1, qb1, qw2, qb2, kw2, kb2, fmask, ws);
    nfh_main<<<B_TOT / NB, 256, 0, stream>>>(
        rss, feat, pos, prev,
        gw1, gb1, gw2, gb2, kw1, kb1,
        sigma, ws, out);
}

// Round 3
// 203.213 us; speedup vs baseline: 1.0483x; 1.0483x over previous
//
#include <hip/hip_runtime.h>

#define B_TOT 65536
#define R 12
#define L 16
#define NB 16
#define NEG_MIN -3.402823466e38f

// ws layout (float index):
//   [0,32)   v[j]  (kw2 . qb2)
//   [32]     c     (qb2 . kb2)
//   [40,52)  pmask (as int: bit l set if freq_mask[r][l] != 0)
//   [64,96)  sorted breakpoints t[32]
//   [96, 96+33*72) interval table: row m (72 floats, 288 B):
//        [0,32) A_m   [32] Au_m   [33,36) pad
//        [36,68) B_m  [68] Bu_m   [69,72) pad
#define WS_V   0
#define WS_C   32
#define WS_PM  40
#define WS_BP  64
#define WS_TAB 96
#define TROW   72

// LDS strides
#define BH_LSTRIDE 36
#define BH_BSTRIDE 580
#define VB_STRIDE  17

__global__ __launch_bounds__(256) void nfh_pre(
    const float* __restrict__ qw1, const float* __restrict__ qb1,
    const float* __restrict__ qw2, const float* __restrict__ qb2,
    const float* __restrict__ kw2, const float* __restrict__ kb2,
    const int*   __restrict__ fmask,
    float* __restrict__ ws)
{
    __shared__ float sM[1024];
    __shared__ float su[32];
    __shared__ float sw1[32], sb1[32], sbp[32];
    const int t = threadIdx.x;

    if (t < 32) { sw1[t] = qw1[t]; sb1[t] = qb1[t]; }
    for (int e = t; e < 1024; e += 256) {
        const int i = e >> 5, j = e & 31;
        float acc = 0.f;
        for (int h = 0; h < 64; ++h) acc = fmaf(qw2[i * 64 + h], kw2[j * 64 + h], acc);
        sM[e] = acc;
    }
    if (t < 32) {
        float au = 0.f, av = 0.f;
        for (int h = 0; h < 64; ++h) {
            au = fmaf(qw2[t * 64 + h], kb2[h], au);
            av = fmaf(kw2[t * 64 + h], qb2[h], av);
        }
        su[t] = au;
        ws[WS_V + t] = av;
        const float w = qw1[t];
        sbp[t] = (w != 0.f) ? (-qb1[t] / w) : 3.0e30f;
    }
    if (t == 64) {
        float acc = 0.f;
        for (int h = 0; h < 64; ++h) acc = fmaf(qb2[h], kb2[h], acc);
        ws[WS_C] = acc;
    }
    if (t < 12) {
        int pm = 0;
        for (int l = 0; l < 16; ++l) if (fmask[t * 16 + l] != 0) pm |= (1 << l);
        ((int*)ws)[WS_PM + t] = pm;
    }
    __syncthreads();
    if (t == 0) {
        for (int i = 1; i < 32; ++i) {
            float key = sbp[i]; int j = i - 1;
            while (j >= 0 && sbp[j] > key) { sbp[j + 1] = sbp[j]; --j; }
            sbp[j + 1] = key;
        }
    }
    __syncthreads();
    if (t < 32) ws[WS_BP + t] = sbp[t];

    for (int task = t; task < 33 * 32 + 33; task += 256) {
        const int m = (task < 33 * 32) ? (task >> 5) : (task - 33 * 32);
        const float xi = (m == 0) ? sbp[0] - 1.f
                       : ((m == 32) ? sbp[31] + 1.f
                                    : sbp[m - 1] + 0.5f * (sbp[m] - sbp[m - 1]));
        if (task < 33 * 32) {
            const int j = task & 31;
            float A = 0.f, Bv = 0.f;
            for (int i = 0; i < 32; ++i) {
                if (fmaf(sw1[i], xi, sb1[i]) > 0.f) {
                    A  = fmaf(sw1[i], sM[i * 32 + j], A);
                    Bv = fmaf(sb1[i], sM[i * 32 + j], Bv);
                }
            }
            ws[WS_TAB + m * TROW + j] = A;
            ws[WS_TAB + m * TROW + 36 + j] = Bv;
        } else {
            float Au = 0.f, Bu = 0.f;
            for (int i = 0; i < 32; ++i) {
                if (fmaf(sw1[i], xi, sb1[i]) > 0.f) {
                    Au = fmaf(sw1[i], su[i], Au);
                    Bu = fmaf(sb1[i], su[i], Bu);
                }
            }
            ws[WS_TAB + m * TROW + 32] = Au;
            ws[WS_TAB + m * TROW + 36 + 32] = Bu;
        }
    }
}

__global__ __launch_bounds__(256) void nfh_main(
    const float* __restrict__ rss,   // [B,R]
    const float* __restrict__ feat,  // [B,L,F]
    const float* __restrict__ pos,   // [B,L,3]
    const float* __restrict__ prev,  // [B,3]
    const float* __restrict__ gw1, const float* __restrict__ gb1,
    const float* __restrict__ gw2, const float* __restrict__ gb2,
    const float* __restrict__ kw1, const float* __restrict__ kb1,
    const float* __restrict__ sigma_p,
    const float* __restrict__ ws,
    float* __restrict__ out)
{
    __shared__ float s_bh[NB * BH_BSTRIDE];   // key hiddens, padded (r1 layout: 0 conflicts)
    __shared__ float s_vb[NB * VB_STRIDE];    // vb + c - dist^2/(2s^2), stride 17 (bank-spread)
    __shared__ float s_xq[NB * R];

    const int t = threadIdx.x;
    const int b0 = blockIdx.x * NB;
    const float sigma = sigma_p[0];
    const float inv2s2 = 1.f / (2.f * sigma * sigma);

    // ---------- P1: t = (bb1, l1): key hidden -> LDS ----------
    {
        const int bb1 = t >> 4, l1 = t & 15;
        const int b = b0 + bb1;
        float in[11];
        const float4* f4 = (const float4*)(feat + ((size_t)b * (L * 8) + l1 * 8));
        const float4 fa = f4[0], fb = f4[1];
        in[0] = fa.x; in[1] = fa.y; in[2] = fa.z; in[3] = fa.w;
        in[4] = fb.x; in[5] = fb.y; in[6] = fb.z; in[7] = fb.w;
        const float* pp = pos + ((size_t)b * (L * 3) + l1 * 3);
        in[8] = pp[0]; in[9] = pp[1]; in[10] = pp[2];

        float dsq = 0.f;
        #pragma unroll
        for (int m = 0; m < 3; ++m) {
            const float d = prev[b * 3 + m] - in[8 + m];
            dsq = fmaf(d, d, dsq);
        }
        float bh[32];
        #pragma unroll
        for (int j = 0; j < 32; ++j) bh[j] = kb1[j];
        #pragma unroll
        for (int m = 0; m < 11; ++m) {
            const float im = in[m];
            #pragma unroll
            for (int j = 0; j < 32; ++j) bh[j] = fmaf(im, kw1[m * 32 + j], bh[j]);
        }
        float vb = ws[WS_C];
        #pragma unroll
        for (int j = 0; j < 32; ++j) {
            bh[j] = fmaxf(bh[j], 0.f);
            vb = fmaf(ws[WS_V + j], bh[j], vb);
        }
        s_vb[bb1 * VB_STRIDE + l1] = vb - dsq * inv2s2;

        float4* dst = (float4*)&s_bh[bb1 * BH_BSTRIDE + l1 * BH_LSTRIDE];
        #pragma unroll
        for (int q = 0; q < 8; ++q)
            dst[q] = make_float4(bh[q * 4], bh[q * 4 + 1], bh[q * 4 + 2], bh[q * 4 + 3]);
    }

    // ---------- P2a: t < 192 = (bb, r): gate -> iw, xq -> LDS ----------
    if (t < NB * R) {
        const float x = rss[(size_t)b0 * R + t];
        float z = gb2[0];
        #pragma unroll
        for (int i = 0; i < 16; ++i) {
            const float h = fmaxf(fmaf(x, gw1[i], gb1[i]), 0.f);
            z = fmaf(h, gw2[i], z);
        }
        const float gate = 1.f / (1.f + __expf(-z));
        const float iw = (x > 0.5f) ? gate : 0.f;
        out[(size_t)B_TOT * R * L + (size_t)b0 * R + t] = iw;
        s_xq[t] = x * iw;
    }
    __syncthreads();

    // ---------- P2b: last wave (t >= 192): 64 threads = (bb, rg), 3 r's each ----------
    const int t2 = t - 192;
    if (t2 >= 0) {
        const int bb = t2 >> 2, rg = t2 & 3;
        const int b = b0 + bb;

        float tt[3][32];
        float tc[3];
        #pragma unroll
        for (int ri = 0; ri < 3; ++ri) {
            const int r = rg * 3 + ri;
            const float xq = s_xq[bb * R + r];
            int k = 0;
            #pragma unroll
            for (int m = 0; m < 32; ++m) k += (xq > ws[WS_BP + m]) ? 1 : 0;
            const float* row = ws + WS_TAB + k * TROW;
            const float4* ra = (const float4*)row;
            const float4* rb = (const float4*)(row + 36);
            tc[ri] = fmaf(xq, row[32], row[68]);
            #pragma unroll
            for (int q = 0; q < 8; ++q) {
                const float4 a4 = ra[q], b4 = rb[q];
                tt[ri][q * 4 + 0] = fmaf(xq, a4.x, b4.x);
                tt[ri][q * 4 + 1] = fmaf(xq, a4.y, b4.y);
                tt[ri][q * 4 + 2] = fmaf(xq, a4.z, b4.z);
                tt[ri][q * 4 + 3] = fmaf(xq, a4.w, b4.w);
            }
        }

        float sc[3][16];
        const float* bhp = &s_bh[bb * BH_BSTRIDE];
        #pragma unroll
        for (int l = 0; l < 16; ++l) {
            const float4* bp4 = (const float4*)&bhp[l * BH_LSTRIDE];
            const float vb = s_vb[bb * VB_STRIDE + l];
            float a0 = vb + tc[0], a1 = vb + tc[1], a2 = vb + tc[2];
            #pragma unroll
            for (int q = 0; q < 8; ++q) {
                const float4 v4 = bp4[q];
                a0 = fmaf(tt[0][q * 4 + 0], v4.x, a0);
                a1 = fmaf(tt[1][q * 4 + 0], v4.x, a1);
                a2 = fmaf(tt[2][q * 4 + 0], v4.x, a2);
                a0 = fmaf(tt[0][q * 4 + 1], v4.y, a0);
                a1 = fmaf(tt[1][q * 4 + 1], v4.y, a1);
                a2 = fmaf(tt[2][q * 4 + 1], v4.y, a2);
                a0 = fmaf(tt[0][q * 4 + 2], v4.z, a0);
                a1 = fmaf(tt[1][q * 4 + 2], v4.z, a1);
                a2 = fmaf(tt[2][q * 4 + 2], v4.z, a2);
                a0 = fmaf(tt[0][q * 4 + 3], v4.w, a0);
                a1 = fmaf(tt[1][q * 4 + 3], v4.w, a1);
                a2 = fmaf(tt[2][q * 4 + 3], v4.w, a2);
            }
            sc[0][l] = a0; sc[1][l] = a1; sc[2][l] = a2;
        }

        #pragma unroll
        for (int ri = 0; ri < 3; ++ri) {
            const int r = rg * 3 + ri;
            const int pm = ((const int*)ws)[WS_PM + r];
            #pragma unroll
            for (int l = 0; l < 16; ++l)
                if (!((pm >> l) & 1)) sc[ri][l] = NEG_MIN;
            float mx = sc[ri][0];
            #pragma unroll
            for (int l = 1; l < 16; ++l) mx = fmaxf(mx, sc[ri][l]);
            float sum = 0.f;
            #pragma unroll
            for (int l = 0; l < 16; ++l) { sc[ri][l] = __expf(sc[ri][l] - mx); sum += sc[ri][l]; }
            const float inv = 1.f / sum;

            float4* op4 = (float4*)(out + (size_t)((size_t)b * R + r) * L);
            #pragma unroll
            for (int q = 0; q < 4; ++q)
                op4[q] = make_float4(sc[ri][q * 4 + 0] * inv, sc[ri][q * 4 + 1] * inv,
                                     sc[ri][q * 4 + 2] * inv, sc[ri][q * 4 + 3] * inv);
        }
    }
}

extern "C" void kernel_launch(void* const* d_in, const int* in_sizes, int n_in,
                              void* d_out, int out_size, void* d_ws, size_t ws_size,
                              hipStream_t stream) {
    const float* rss   = (const float*)d_in[0];
    const float* feat  = (const float*)d_in[1];
    const float* pos   = (const float*)d_in[2];
    const float* prev  = (const float*)d_in[3];
    const int*   fmask = (const int*)d_in[4];
    const float* gw1   = (const float*)d_in[5];
    const float* gb1   = (const float*)d_in[6];
    const float* gw2   = (const float*)d_in[7];
    const float* gb2   = (const float*)d_in[8];
    const float* qw1   = (const float*)d_in[9];
    const float* qb1   = (const float*)d_in[10];
    const float* qw2   = (const float*)d_in[11];
    const float* qb2   = (const float*)d_in[12];
    const float* kw1   = (const float*)d_in[13];
    const float* kb1   = (const float*)d_in[14];
    const float* kw2   = (const float*)d_in[15];
    const float* kb2   = (const float*)d_in[16];
    const float* sigma = (const float*)d_in[17];
    float* out = (float*)d_out;
    float* ws  = (float*)d_ws;

    nfh_pre<<<1, 256, 0, stream>>>(qw1, qb1, qw2, qb2, kw2, kb2, fmask, ws);
    nfh_main<<<B_TOT / NB, 256, 0, stream>>>(
        rss, feat, pos, prev,
        gw1, gb1, gw2, gb2, kw1, kb1,
        sigma, ws, out);
}

// Round 4
// 198.750 us; speedup vs baseline: 1.0718x; 1.0225x over previous
//
#include <hip/hip_runtime.h>

#define B_TOT 65536
#define R 12
#define L 16
#define NB 16
#define NEG_MIN -3.402823466e38f

// ws layout (float index):
//   [0,32)   v[j]  (kw2 . qb2)
//   [32]     c     (qb2 . kb2)
//   [40,52)  pmask (as int: bit l set if freq_mask[r][l] != 0)
//   [64,96)  sorted breakpoints t[32]
//   [96, 96+33*72) interval table: row m (72 floats, 288 B):
//        [0,32) A_m   [32] Au_m   [33,36) pad
//        [36,68) B_m  [68] Bu_m   [69,72) pad
#define WS_V   0
#define WS_C   32
#define WS_PM  40
#define WS_BP  64
#define WS_TAB 96
#define TROW   72

// LDS strides (r1-proven: 0 bank conflicts on score reads)
#define BH_LSTRIDE 36
#define BH_BSTRIDE 580
#define VB_STRIDE  17

__global__ __launch_bounds__(256) void nfh_pre(
    const float* __restrict__ qw1, const float* __restrict__ qb1,
    const float* __restrict__ qw2, const float* __restrict__ qb2,
    const float* __restrict__ kw2, const float* __restrict__ kb2,
    const int*   __restrict__ fmask,
    float* __restrict__ ws)
{
    __shared__ float sM[1024];
    __shared__ float su[32];
    __shared__ float sw1[32], sb1[32], sbp[32];
    const int t = threadIdx.x;

    if (t < 32) { sw1[t] = qw1[t]; sb1[t] = qb1[t]; }
    for (int e = t; e < 1024; e += 256) {
        const int i = e >> 5, j = e & 31;
        float acc = 0.f;
        for (int h = 0; h < 64; ++h) acc = fmaf(qw2[i * 64 + h], kw2[j * 64 + h], acc);
        sM[e] = acc;
    }
    if (t < 32) {
        float au = 0.f, av = 0.f;
        for (int h = 0; h < 64; ++h) {
            au = fmaf(qw2[t * 64 + h], kb2[h], au);
            av = fmaf(kw2[t * 64 + h], qb2[h], av);
        }
        su[t] = au;
        ws[WS_V + t] = av;
        const float w = qw1[t];
        sbp[t] = (w != 0.f) ? (-qb1[t] / w) : 3.0e30f;
    }
    if (t == 64) {
        float acc = 0.f;
        for (int h = 0; h < 64; ++h) acc = fmaf(qb2[h], kb2[h], acc);
        ws[WS_C] = acc;
    }
    if (t < 12) {
        int pm = 0;
        for (int l = 0; l < 16; ++l) if (fmask[t * 16 + l] != 0) pm |= (1 << l);
        ((int*)ws)[WS_PM + t] = pm;
    }
    __syncthreads();
    if (t == 0) {
        for (int i = 1; i < 32; ++i) {
            float key = sbp[i]; int j = i - 1;
            while (j >= 0 && sbp[j] > key) { sbp[j + 1] = sbp[j]; --j; }
            sbp[j + 1] = key;
        }
    }
    __syncthreads();
    if (t < 32) ws[WS_BP + t] = sbp[t];

    for (int task = t; task < 33 * 32 + 33; task += 256) {
        const int m = (task < 33 * 32) ? (task >> 5) : (task - 33 * 32);
        const float xi = (m == 0) ? sbp[0] - 1.f
                       : ((m == 32) ? sbp[31] + 1.f
                                    : sbp[m - 1] + 0.5f * (sbp[m] - sbp[m - 1]));
        if (task < 33 * 32) {
            const int j = task & 31;
            float A = 0.f, Bv = 0.f;
            for (int i = 0; i < 32; ++i) {
                if (fmaf(sw1[i], xi, sb1[i]) > 0.f) {
                    A  = fmaf(sw1[i], sM[i * 32 + j], A);
                    Bv = fmaf(sb1[i], sM[i * 32 + j], Bv);
                }
            }
            ws[WS_TAB + m * TROW + j] = A;
            ws[WS_TAB + m * TROW + 36 + j] = Bv;
        } else {
            float Au = 0.f, Bu = 0.f;
            for (int i = 0; i < 32; ++i) {
                if (fmaf(sw1[i], xi, sb1[i]) > 0.f) {
                    Au = fmaf(sw1[i], su[i], Au);
                    Bu = fmaf(sb1[i], su[i], Bu);
                }
            }
            ws[WS_TAB + m * TROW + 32] = Au;
            ws[WS_TAB + m * TROW + 36 + 32] = Bu;
        }
    }
}

// min 3 waves/EU -> VGPR cap ~170: enough for tt0/tt1/sc0/sc1 without spilling
__global__ __launch_bounds__(256, 3) void nfh_main(
    const float* __restrict__ rss,   // [B,R]
    const float* __restrict__ feat,  // [B,L,F]
    const float* __restrict__ pos,   // [B,L,3]
    const float* __restrict__ prev,  // [B,3]
    const float* __restrict__ gw1, const float* __restrict__ gb1,
    const float* __restrict__ gw2, const float* __restrict__ gb2,
    const float* __restrict__ kw1, const float* __restrict__ kb1,
    const float* __restrict__ sigma_p,
    const float* __restrict__ ws,
    float* __restrict__ out)
{
    __shared__ float s_bh[NB * BH_BSTRIDE];
    __shared__ float s_vb[NB * VB_STRIDE];
    __shared__ float s_xq[NB * R];

    const int t = threadIdx.x;
    const int b0 = blockIdx.x * NB;
    const float sigma = sigma_p[0];
    const float inv2s2 = 1.f / (2.f * sigma * sigma);

    // ---------- P1: t = (bb1, l1): key hidden -> LDS ----------
    {
        const int bb1 = t >> 4, l1 = t & 15;
        const int b = b0 + bb1;
        float in[11];
        const float4* f4 = (const float4*)(feat + ((size_t)b * (L * 8) + l1 * 8));
        const float4 fa = f4[0], fb = f4[1];
        in[0] = fa.x; in[1] = fa.y; in[2] = fa.z; in[3] = fa.w;
        in[4] = fb.x; in[5] = fb.y; in[6] = fb.z; in[7] = fb.w;
        const float* pp = pos + ((size_t)b * (L * 3) + l1 * 3);
        in[8] = pp[0]; in[9] = pp[1]; in[10] = pp[2];

        float dsq = 0.f;
        #pragma unroll
        for (int m = 0; m < 3; ++m) {
            const float d = prev[b * 3 + m] - in[8 + m];
            dsq = fmaf(d, d, dsq);
        }
        float bh[32];
        #pragma unroll
        for (int j = 0; j < 32; ++j) bh[j] = kb1[j];
        #pragma unroll
        for (int m = 0; m < 11; ++m) {
            const float im = in[m];
            #pragma unroll
            for (int j = 0; j < 32; ++j) bh[j] = fmaf(im, kw1[m * 32 + j], bh[j]);
        }
        float vb = ws[WS_C];
        #pragma unroll
        for (int j = 0; j < 32; ++j) {
            bh[j] = fmaxf(bh[j], 0.f);
            vb = fmaf(ws[WS_V + j], bh[j], vb);
        }
        s_vb[bb1 * VB_STRIDE + l1] = vb - dsq * inv2s2;

        float4* dst = (float4*)&s_bh[bb1 * BH_BSTRIDE + l1 * BH_LSTRIDE];
        #pragma unroll
        for (int q = 0; q < 8; ++q)
            dst[q] = make_float4(bh[q * 4], bh[q * 4 + 1], bh[q * 4 + 2], bh[q * 4 + 3]);
    }

    // ---------- P2a: t < 192 = (bb, r): gate -> iw (store), xq -> LDS ----------
    if (t < NB * R) {
        const float x = rss[(size_t)b0 * R + t];
        float z = gb2[0];
        #pragma unroll
        for (int i = 0; i < 16; ++i) {
            const float h = fmaxf(fmaf(x, gw1[i], gb1[i]), 0.f);
            z = fmaf(h, gw2[i], z);
        }
        const float gate = 1.f / (1.f + __expf(-z));
        const float iw = (x > 0.5f) ? gate : 0.f;
        out[(size_t)B_TOT * R * L + (size_t)b0 * R + t] = iw;
        s_xq[t] = x * iw;
    }
    __syncthreads();

    // ---------- P2b: t < 96 = (rp, bb): 2 r's per thread (r = rp, rp+6) ----------
    if (t < 96) {
        const int rp = t >> 4;   // 0..5
        const int bb = t & 15;   // 0..15
        const int b  = b0 + bb;

        float tt0[32], tt1[32];
        float tc0, tc1;
        {
            const float xq = s_xq[bb * R + rp];
            int k = 0;
            #pragma unroll
            for (int m = 0; m < 32; ++m) k += (xq > ws[WS_BP + m]) ? 1 : 0;
            const float* row = ws + WS_TAB + k * TROW;
            const float4* ra = (const float4*)row;
            const float4* rb = (const float4*)(row + 36);
            tc0 = fmaf(xq, row[32], row[68]);
            #pragma unroll
            for (int q = 0; q < 8; ++q) {
                const float4 a4 = ra[q], b4 = rb[q];
                tt0[q * 4 + 0] = fmaf(xq, a4.x, b4.x);
                tt0[q * 4 + 1] = fmaf(xq, a4.y, b4.y);
                tt0[q * 4 + 2] = fmaf(xq, a4.z, b4.z);
                tt0[q * 4 + 3] = fmaf(xq, a4.w, b4.w);
            }
        }
        {
            const float xq = s_xq[bb * R + rp + 6];
            int k = 0;
            #pragma unroll
            for (int m = 0; m < 32; ++m) k += (xq > ws[WS_BP + m]) ? 1 : 0;
            const float* row = ws + WS_TAB + k * TROW;
            const float4* ra = (const float4*)row;
            const float4* rb = (const float4*)(row + 36);
            tc1 = fmaf(xq, row[32], row[68]);
            #pragma unroll
            for (int q = 0; q < 8; ++q) {
                const float4 a4 = ra[q], b4 = rb[q];
                tt1[q * 4 + 0] = fmaf(xq, a4.x, b4.x);
                tt1[q * 4 + 1] = fmaf(xq, a4.y, b4.y);
                tt1[q * 4 + 2] = fmaf(xq, a4.z, b4.z);
                tt1[q * 4 + 3] = fmaf(xq, a4.w, b4.w);
            }
        }

        float sc0[16], sc1[16];
        const float* bhp = &s_bh[bb * BH_BSTRIDE];
        #pragma unroll
        for (int l = 0; l < 16; ++l) {
            const float4* bp4 = (const float4*)&bhp[l * BH_LSTRIDE];
            const float vb = s_vb[bb * VB_STRIDE + l];
            float a0 = vb + tc0, a1 = vb + tc1;
            #pragma unroll
            for (int q = 0; q < 8; ++q) {
                const float4 v4 = bp4[q];
                a0 = fmaf(tt0[q * 4 + 0], v4.x, a0);
                a1 = fmaf(tt1[q * 4 + 0], v4.x, a1);
                a0 = fmaf(tt0[q * 4 + 1], v4.y, a0);
                a1 = fmaf(tt1[q * 4 + 1], v4.y, a1);
                a0 = fmaf(tt0[q * 4 + 2], v4.z, a0);
                a1 = fmaf(tt1[q * 4 + 2], v4.z, a1);
                a0 = fmaf(tt0[q * 4 + 3], v4.w, a0);
                a1 = fmaf(tt1[q * 4 + 3], v4.w, a1);
            }
            sc0[l] = a0; sc1[l] = a1;
        }

        // softmax + store, r0 then r1
        {
            const int r = rp;
            const int pm = ((const int*)ws)[WS_PM + r];
            #pragma unroll
            for (int l = 0; l < 16; ++l)
                if (!((pm >> l) & 1)) sc0[l] = NEG_MIN;
            float mx = sc0[0];
            #pragma unroll
            for (int l = 1; l < 16; ++l) mx = fmaxf(mx, sc0[l]);
            float sum = 0.f;
            #pragma unroll
            for (int l = 0; l < 16; ++l) { sc0[l] = __expf(sc0[l] - mx); sum += sc0[l]; }
            const float inv = 1.f / sum;
            float4* op4 = (float4*)(out + (size_t)((size_t)b * R + r) * L);
            #pragma unroll
            for (int q = 0; q < 4; ++q)
                op4[q] = make_float4(sc0[q * 4 + 0] * inv, sc0[q * 4 + 1] * inv,
                                     sc0[q * 4 + 2] * inv, sc0[q * 4 + 3] * inv);
        }
        {
            const int r = rp + 6;
            const int pm = ((const int*)ws)[WS_PM + r];
            #pragma unroll
            for (int l = 0; l < 16; ++l)
                if (!((pm >> l) & 1)) sc1[l] = NEG_MIN;
            float mx = sc1[0];
            #pragma unroll
            for (int l = 1; l < 16; ++l) mx = fmaxf(mx, sc1[l]);
            float sum = 0.f;
            #pragma unroll
            for (int l = 0; l < 16; ++l) { sc1[l] = __expf(sc1[l] - mx); sum += sc1[l]; }
            const float inv = 1.f / sum;
            float4* op4 = (float4*)(out + (size_t)((size_t)b * R + r) * L);
            #pragma unroll
            for (int q = 0; q < 4; ++q)
                op4[q] = make_float4(sc1[q * 4 + 0] * inv, sc1[q * 4 + 1] * inv,
                                     sc1[q * 4 + 2] * inv, sc1[q * 4 + 3] * inv);
        }
    }
}

extern "C" void kernel_launch(void* const* d_in, const int* in_sizes, int n_in,
                              void* d_out, int out_size, void* d_ws, size_t ws_size,
                              hipStream_t stream) {
    const float* rss   = (const float*)d_in[0];
    const float* feat  = (const float*)d_in[1];
    const float* pos   = (const float*)d_in[2];
    const float* prev  = (const float*)d_in[3];
    const int*   fmask = (const int*)d_in[4];
    const float* gw1   = (const float*)d_in[5];
    const float* gb1   = (const float*)d_in[6];
    const float* gw2   = (const float*)d_in[7];
    const float* gb2   = (const float*)d_in[8];
    const float* qw1   = (const float*)d_in[9];
    const float* qb1   = (const float*)d_in[10];
    const float* qw2   = (const float*)d_in[11];
    const float* qb2   = (const float*)d_in[12];
    const float* kw1   = (const float*)d_in[13];
    const float* kb1   = (const float*)d_in[14];
    const float* kw2   = (const float*)d_in[15];
    const float* kb2   = (const float*)d_in[16];
    const float* sigma = (const float*)d_in[17];
    float* out = (float*)d_out;
    float* ws  = (float*)d_ws;

    nfh_pre<<<1, 256, 0, stream>>>(qw1, qb1, qw2, qb2, kw2, kb2, fmask, ws);
    nfh_main<<<B_TOT / NB, 256, 0, stream>>>(
        rss, feat, pos, prev,
        gw1, gb1, gw2, gb2, kw1, kb1,
        sigma, ws, out);
}

// Round 5
// 181.578 us; speedup vs baseline: 1.1732x; 1.0946x over previous
//
#include <hip/hip_runtime.h>

#define B_TOT 65536
#define R 12
#define L 16
#define NB 16
#define NEG_MIN -3.402823466e38f

// ws layout (float index):
//   [0,32)   v[j]  (kw2 . qb2)
//   [32]     c     (qb2 . kb2)
//   [40,52)  pmask (as int: bit l set if freq_mask[r][l] != 0)
//   [64,96)  sorted breakpoints t[32]
//   [96, 96+33*72) interval table: row m (72 floats, 288 B):
//        [0,32) A_m   [32] Au_m   [33,36) pad
//        [36,68) B_m  [68] Bu_m   [69,72) pad
#define WS_V   0
#define WS_C   32
#define WS_PM  40
#define WS_BP  64
#define WS_TAB 96
#define TROW   72

typedef __attribute__((ext_vector_type(8))) short short8;
typedef __attribute__((ext_vector_type(4))) float f32x4;

static __device__ __forceinline__ short f2bf(float f) {
    uint32_t u = __float_as_uint(f);
    uint32_t r = u + 0x7FFFu + ((u >> 16) & 1u);  // round-to-nearest-even
    return (short)(r >> 16);
}

__global__ __launch_bounds__(256) void nfh_pre(
    const float* __restrict__ qw1, const float* __restrict__ qb1,
    const float* __restrict__ qw2, const float* __restrict__ qb2,
    const float* __restrict__ kw2, const float* __restrict__ kb2,
    const int*   __restrict__ fmask,
    float* __restrict__ ws)
{
    __shared__ float sM[1024];
    __shared__ float su[32];
    __shared__ float sw1[32], sb1[32], sbp[32];
    const int t = threadIdx.x;

    if (t < 32) { sw1[t] = qw1[t]; sb1[t] = qb1[t]; }
    for (int e = t; e < 1024; e += 256) {
        const int i = e >> 5, j = e & 31;
        float acc = 0.f;
        for (int h = 0; h < 64; ++h) acc = fmaf(qw2[i * 64 + h], kw2[j * 64 + h], acc);
        sM[e] = acc;
    }
    if (t < 32) {
        float au = 0.f, av = 0.f;
        for (int h = 0; h < 64; ++h) {
            au = fmaf(qw2[t * 64 + h], kb2[h], au);
            av = fmaf(kw2[t * 64 + h], qb2[h], av);
        }
        su[t] = au;
        ws[WS_V + t] = av;
        const float w = qw1[t];
        sbp[t] = (w != 0.f) ? (-qb1[t] / w) : 3.0e30f;
    }
    if (t == 64) {
        float acc = 0.f;
        for (int h = 0; h < 64; ++h) acc = fmaf(qb2[h], kb2[h], acc);
        ws[WS_C] = acc;
    }
    if (t < 12) {
        int pm = 0;
        for (int l = 0; l < 16; ++l) if (fmask[t * 16 + l] != 0) pm |= (1 << l);
        ((int*)ws)[WS_PM + t] = pm;
    }
    __syncthreads();
    if (t == 0) {
        for (int i = 1; i < 32; ++i) {
            float key = sbp[i]; int j = i - 1;
            while (j >= 0 && sbp[j] > key) { sbp[j + 1] = sbp[j]; --j; }
            sbp[j + 1] = key;
        }
    }
    __syncthreads();
    if (t < 32) ws[WS_BP + t] = sbp[t];

    for (int task = t; task < 33 * 32 + 33; task += 256) {
        const int m = (task < 33 * 32) ? (task >> 5) : (task - 33 * 32);
        const float xi = (m == 0) ? sbp[0] - 1.f
                       : ((m == 32) ? sbp[31] + 1.f
                                    : sbp[m - 1] + 0.5f * (sbp[m] - sbp[m - 1]));
        if (task < 33 * 32) {
            const int j = task & 31;
            float A = 0.f, Bv = 0.f;
            for (int i = 0; i < 32; ++i) {
                if (fmaf(sw1[i], xi, sb1[i]) > 0.f) {
                    A  = fmaf(sw1[i], sM[i * 32 + j], A);
                    Bv = fmaf(sb1[i], sM[i * 32 + j], Bv);
                }
            }
            ws[WS_TAB + m * TROW + j] = A;
            ws[WS_TAB + m * TROW + 36 + j] = Bv;
        } else {
            float Au = 0.f, Bu = 0.f;
            for (int i = 0; i < 32; ++i) {
                if (fmaf(sw1[i], xi, sb1[i]) > 0.f) {
                    Au = fmaf(sw1[i], su[i], Au);
                    Bu = fmaf(sb1[i], su[i], Bu);
                }
            }
            ws[WS_TAB + m * TROW + 32] = Au;
            ws[WS_TAB + m * TROW + 36 + 32] = Bu;
        }
    }
}

__global__ __launch_bounds__(256) void nfh_main(
    const float* __restrict__ rss,   // [B,R]
    const float* __restrict__ feat,  // [B,L,F]
    const float* __restrict__ pos,   // [B,L,3]
    const float* __restrict__ prev,  // [B,3]
    const float* __restrict__ gw1, const float* __restrict__ gb1,
    const float* __restrict__ gw2, const float* __restrict__ gb2,
    const float* __restrict__ kw1, const float* __restrict__ kb1,
    const float* __restrict__ sigma_p,
    const float* __restrict__ ws,
    float* __restrict__ out)
{
    // MFMA operand fragments, built directly in lane order:
    // A-frag (bh):  lane = kblock*16 + l, holds bh[l][kblock*8 .. +7]
    // B-frag (tt):  lane = kblock*16 + r, holds tt[r][kblock*8 .. +7]
    __shared__ short s_bhf[NB * 512];  // 16 KB
    __shared__ short s_ttf[NB * 512];  // 16 KB
    __shared__ float s_vb[NB * 16];
    __shared__ float s_tc[NB * 16];
    __shared__ int   s_pm[16];

    const int t = threadIdx.x;
    const int b0 = blockIdx.x * NB;
    const float sigma = sigma_p[0];
    const float inv2s2 = 1.f / (2.f * sigma * sigma);

    if (t < 16) s_pm[t] = (t < 12) ? ((const int*)ws)[WS_PM + t] : 0;

    // ---------- P1: all 256 threads = (bb1, l1): key MLP -> bf16 A-frag ----------
    {
        const int bb1 = t >> 4, l1 = t & 15;
        const int b = b0 + bb1;
        float in[11];
        const float4* f4 = (const float4*)(feat + ((size_t)b * (L * 8) + l1 * 8));
        const float4 fa = f4[0], fb = f4[1];
        in[0] = fa.x; in[1] = fa.y; in[2] = fa.z; in[3] = fa.w;
        in[4] = fb.x; in[5] = fb.y; in[6] = fb.z; in[7] = fb.w;
        const float* pp = pos + ((size_t)b * (L * 3) + l1 * 3);
        in[8] = pp[0]; in[9] = pp[1]; in[10] = pp[2];

        float dsq = 0.f;
        #pragma unroll
        for (int m = 0; m < 3; ++m) {
            const float d = prev[b * 3 + m] - in[8 + m];
            dsq = fmaf(d, d, dsq);
        }
        float bh[32];
        #pragma unroll
        for (int j = 0; j < 32; ++j) bh[j] = kb1[j];
        #pragma unroll
        for (int m = 0; m < 11; ++m) {
            const float im = in[m];
            #pragma unroll
            for (int j = 0; j < 32; ++j) bh[j] = fmaf(im, kw1[m * 32 + j], bh[j]);
        }
        float vb = ws[WS_C];
        #pragma unroll
        for (int j = 0; j < 32; ++j) {
            bh[j] = fmaxf(bh[j], 0.f);
            vb = fmaf(ws[WS_V + j], bh[j], vb);
        }
        s_vb[bb1 * 16 + l1] = vb - dsq * inv2s2;

        #pragma unroll
        for (int kb = 0; kb < 4; ++kb) {
            short8 pk;
            #pragma unroll
            for (int j = 0; j < 8; ++j) pk[j] = f2bf(bh[kb * 8 + j]);
            *(short8*)&s_bhf[bb1 * 512 + (kb * 16 + l1) * 8] = pk;
        }
    }

    // ---------- P2a: t < 192 = (bb2, r2): gate -> iw, tt lookup -> bf16 B-frag ----
    if (t < NB * R) {
        const int bb2 = t / R;
        const int r2 = t - bb2 * R;
        const float x = rss[(size_t)b0 * R + t];
        float z = gb2[0];
        #pragma unroll
        for (int i = 0; i < 16; ++i) {
            const float h = fmaxf(fmaf(x, gw1[i], gb1[i]), 0.f);
            z = fmaf(h, gw2[i], z);
        }
        const float gate = 1.f / (1.f + __expf(-z));
        const float iw = (x > 0.5f) ? gate : 0.f;
        out[(size_t)B_TOT * R * L + (size_t)b0 * R + t] = iw;
        const float xq = x * iw;

        int k = 0;
        #pragma unroll
        for (int m = 0; m < 32; ++m) k += (xq > ws[WS_BP + m]) ? 1 : 0;
        const float* row = ws + WS_TAB + k * TROW;
        const float4* ra = (const float4*)row;
        const float4* rb = (const float4*)(row + 36);
        s_tc[bb2 * 16 + r2] = fmaf(xq, row[32], row[68]);
        #pragma unroll
        for (int kb = 0; kb < 4; ++kb) {
            const float4 a0 = ra[kb * 2], b0_ = rb[kb * 2];
            const float4 a1 = ra[kb * 2 + 1], b1_ = rb[kb * 2 + 1];
            short8 pk;
            pk[0] = f2bf(fmaf(xq, a0.x, b0_.x));
            pk[1] = f2bf(fmaf(xq, a0.y, b0_.y));
            pk[2] = f2bf(fmaf(xq, a0.z, b0_.z));
            pk[3] = f2bf(fmaf(xq, a0.w, b0_.w));
            pk[4] = f2bf(fmaf(xq, a1.x, b1_.x));
            pk[5] = f2bf(fmaf(xq, a1.y, b1_.y));
            pk[6] = f2bf(fmaf(xq, a1.z, b1_.z));
            pk[7] = f2bf(fmaf(xq, a1.w, b1_.w));
            *(short8*)&s_ttf[bb2 * 512 + (kb * 16 + r2) * 8] = pk;
        }
    } else {
        // t in [192,256): zero the padded B-frag rows r=12..15 (and tc)
        const int u = t - 192;
        const int bb = u >> 2, r = 12 + (u & 3);
        const short8 z8 = {0, 0, 0, 0, 0, 0, 0, 0};
        #pragma unroll
        for (int kb = 0; kb < 4; ++kb)
            *(short8*)&s_ttf[bb * 512 + (kb * 16 + r) * 8] = z8;
        s_tc[bb * 16 + r] = 0.f;
    }
    __syncthreads();

    // ---------- P3: wave w handles batches w*4 .. w*4+3: 1 MFMA each ----------
    {
        const int lane = t & 63;
        const int w = t >> 6;
        const int r = lane & 15;
        const int lg = lane >> 4;
        const int pm = s_pm[r];

        #pragma unroll
        for (int i = 0; i < 4; ++i) {
            const int bb = w * 4 + i;
            const short8 af = *(const short8*)&s_bhf[bb * 512 + lane * 8];
            const short8 bf = *(const short8*)&s_ttf[bb * 512 + lane * 8];
            f32x4 acc = {0.f, 0.f, 0.f, 0.f};
            acc = __builtin_amdgcn_mfma_f32_16x16x32_bf16(af, bf, acc, 0, 0, 0);

            const float tc = s_tc[bb * 16 + r];
            const f32x4 vb4 = *(const f32x4*)&s_vb[bb * 16 + lg * 4];

            float sc[4];
            #pragma unroll
            for (int j = 0; j < 4; ++j) {
                sc[j] = acc[j] + tc + vb4[j];
                if (!((pm >> (lg * 4 + j)) & 1)) sc[j] = NEG_MIN;
            }
            float mx = fmaxf(fmaxf(sc[0], sc[1]), fmaxf(sc[2], sc[3]));
            mx = fmaxf(mx, __shfl_xor(mx, 16));
            mx = fmaxf(mx, __shfl_xor(mx, 32));
            float sum = 0.f;
            #pragma unroll
            for (int j = 0; j < 4; ++j) { sc[j] = __expf(sc[j] - mx); sum += sc[j]; }
            sum += __shfl_xor(sum, 16);
            sum += __shfl_xor(sum, 32);
            const float inv = 1.f / sum;

            if (r < R) {
                float4* op = (float4*)(out + ((size_t)(b0 + bb) * R + r) * L + lg * 4);
                *op = make_float4(sc[0] * inv, sc[1] * inv, sc[2] * inv, sc[3] * inv);
            }
        }
    }
}

extern "C" void kernel_launch(void* const* d_in, const int* in_sizes, int n_in,
                              void* d_out, int out_size, void* d_ws, size_t ws_size,
                              hipStream_t stream) {
    const float* rss   = (const float*)d_in[0];
    const float* feat  = (const float*)d_in[1];
    const float* pos   = (const float*)d_in[2];
    const float* prev  = (const float*)d_in[3];
    const int*   fmask = (const int*)d_in[4];
    const float* gw1   = (const float*)d_in[5];
    const float* gb1   = (const float*)d_in[6];
    const float* gw2   = (const float*)d_in[7];
    const float* gb2   = (const float*)d_in[8];
    const float* qw1   = (const float*)d_in[9];
    const float* qb1   = (const float*)d_in[10];
    const float* qw2   = (const float*)d_in[11];
    const float* qb2   = (const float*)d_in[12];
    const float* kw1   = (const float*)d_in[13];
    const float* kb1   = (const float*)d_in[14];
    const float* kw2   = (const float*)d_in[15];
    const float* kb2   = (const float*)d_in[16];
    const float* sigma = (const float*)d_in[17];
    float* out = (float*)d_out;
    float* ws  = (float*)d_ws;

    nfh_pre<<<1, 256, 0, stream>>>(qw1, qb1, qw2, qb2, kw2, kb2, fmask, ws);
    nfh_main<<<B_TOT / NB, 256, 0, stream>>>(
        rss, feat, pos, prev,
        gw1, gb1, gw2, gb2, kw1, kb1,
        sigma, ws, out);
}